// Round 8
// baseline (9172.315 us; speedup 1.0000x reference)
//
#include <hip/hip_runtime.h>
#include <math.h>

#define T_STEPS 1024
#define NB 64        // batch
#define NH 512       // hidden
#define NI 256       // input

#define NGRP 4           // batch groups
#define BPG 16           // batches per group (= MFMA M)
#define WGS_PER_GRP 4    // h-split WGs per group (128 h each)

// d_ws layout
#define WS_YBUF_OFF 4096                       // double-buffered bf16 y: 2*64*512
#define WS_INIT_BYTES (WS_YBUF_OFF + NB*NH*2)  // flags + y slot 0 zeroed

typedef short short8 __attribute__((ext_vector_type(8)));
typedef float f32x4 __attribute__((ext_vector_type(4)));
typedef unsigned long long u64x2 __attribute__((ext_vector_type(2)));

__device__ __forceinline__ unsigned short f32_to_bf16(float x) {
    unsigned u = __float_as_uint(x);
    u += 0x7FFFu + ((u >> 16) & 1u);   // round-to-nearest-even
    return (unsigned short)(u >> 16);
}

__device__ __forceinline__ float tanh_fast(float x) {
    x = fminf(15.f, fmaxf(-15.f, x));
    const float ex = __expf(-2.f * x);
    return __fdividef(1.f - ex, 1.f + ex);
}

// ---------------------------------------------------------------------------
// Kernel 1: ext[t,b,h] = inputs[t,b,:] @ W_ih[:,h] + b_ih[h], written to d_out.
// ---------------------------------------------------------------------------
__global__ __launch_bounds__(256) void ext_gemm_kernel(
    const float* __restrict__ inputs, const float* __restrict__ W_ih,
    const float* __restrict__ b_ih, float* __restrict__ out)
{
    __shared__ float Wt[NI * 64];   // [i][h], 64 KiB
    const int tid    = threadIdx.x;
    const int hgrp   = blockIdx.x & 7;
    const int rowgrp = blockIdx.x >> 3;
    const int hbase  = hgrp * 64;
    const long rowbase = (long)rowgrp * 512;

    for (int idx = tid; idx < NI * 64; idx += 256) {
        int i  = idx >> 6;
        int hh = idx & 63;
        Wt[idx] = W_ih[(size_t)i * NH + hbase + hh];
    }
    const int hq = tid & 15;
    const int r  = tid >> 4;
    const float4 bias = *(const float4*)&b_ih[hbase + hq * 4];
    __syncthreads();

    for (int rc = 0; rc < 32; ++rc) {
        const long row = rowbase + rc * 16 + r;
        const float* __restrict__ inrow = inputs + row * NI;
        float ax = 0.f, ay = 0.f, az = 0.f, aw = 0.f;
        #pragma unroll 4
        for (int i = 0; i < NI; i += 4) {
            const float4 a  = *(const float4*)(inrow + i);
            const float4 w0 = *(const float4*)&Wt[(i + 0) * 64 + hq * 4];
            const float4 w1 = *(const float4*)&Wt[(i + 1) * 64 + hq * 4];
            const float4 w2 = *(const float4*)&Wt[(i + 2) * 64 + hq * 4];
            const float4 w3 = *(const float4*)&Wt[(i + 3) * 64 + hq * 4];
            ax += a.x * w0.x + a.y * w1.x + a.z * w2.x + a.w * w3.x;
            ay += a.x * w0.y + a.y * w1.y + a.z * w2.y + a.w * w3.y;
            az += a.x * w0.z + a.y * w1.z + a.z * w2.z + a.w * w3.z;
            aw += a.x * w0.w + a.y * w1.w + a.z * w2.w + a.w * w3.w;
        }
        float4 o = make_float4(ax + bias.x, ay + bias.y, az + bias.z, aw + bias.w);
        *(float4*)&out[row * NH + hbase + hq * 4] = o;
    }
}

// ---------------------------------------------------------------------------
// Kernel 2: MFMA recurrent scan. 16 WGs x 512 threads, 1 WG/CU (128 KiB LDS).
//   grp = bid & 3 (16-batch group), wgi = bid >> 2 (128-h slice).
// W_hh lives in LDS in MFMA-FRAGMENT ORDER: Wf[wave][kb][lane] (staged once).
//   Per-kb B-frag read = ds_read_b128 at lane*16 + kb*1024: linear, zero bank
//   conflicts, immune to cache invalidation, zero VGPR pressure.
// Cross-WG protocol (NO fences — no per-step L2 writeback/invalidate):
//   writer: relaxed agent atomic y-stores (write-through) -> vmcnt(0) ->
//           __syncthreads -> relaxed agent flag store.
//   reader: tid0 relaxed-polls 4 flags -> __syncthreads -> y read as relaxed
//           agent atomic b64 loads (bypass L1/L2, so no stale data possible).
// x-stores / e-loads are private per WG -> plain cached path.
// ---------------------------------------------------------------------------
__global__ __launch_bounds__(512, 1) void horn_recurrent_kernel(
    const float* __restrict__ W_hh, const float* __restrict__ b_hh,
    const float* __restrict__ alpha, const float* __restrict__ omega,
    const float* __restrict__ gamma, const float* __restrict__ v,
    float* __restrict__ out, unsigned short* __restrict__ ybuf,
    unsigned* __restrict__ flags)
{
    __shared__ short8 Wf[8][16][64];   // [wave][kb][lane], 128 KiB

    const int tid  = threadIdx.x;
    const int wave = tid >> 6;
    const int lane = tid & 63;
    const int g    = lane >> 4;   // 0..3 (k sub-slot / batch quad)
    const int c    = lane & 15;   // h within tile (A-row batch for loads)

    const int grp   = blockIdx.x & (NGRP - 1);
    const int wgi   = blockIdx.x >> 2;
    const int bbase = grp * BPG;
    const int h     = wgi * 128 + wave * 16 + c;   // global h column

    // ---- stage W_hh -> LDS fragments (once) ----
    // Wf[wave][kb][g*16+c][j] = bf16(W_hh[kb*32 + 8g + j][h]); the k mapping
    // myk(g,j)=8g+j is identical on A and B sides so it cancels in the dot.
    for (int kb = 0; kb < 16; ++kb) {
        const float* wp = W_hh + (size_t)(kb * 32 + 8 * g) * NH + h;
        short8 f;
        #pragma unroll
        for (int j = 0; j < 8; ++j)
            f[j] = (short)f32_to_bf16(wp[(size_t)j * NH]);
        Wf[wave][kb][lane] = f;
    }

    const float bhh_r = b_hh[h];
    const float al_r  = alpha[h];
    const float omv   = omega[h];
    const float om2_r = omv * omv;
    const float g2_r  = 2.0f * gamma[h];
    const float v_r   = v[h];
    const float gain  = 0.04419417382415922f;   // 1/sqrt(512)
    const float hdt   = 0.1f;

    // named per-lane state (4 C-rows: batches bbase+4g .. +3)
    float x0 = 0.f, x1 = 0.f, x2 = 0.f, x3 = 0.f;
    float y0 = 0.f, y1 = 0.f, y2 = 0.f, y3 = 0.f;
    float e0, e1, e2, e3;

    // prologue: prefetch e[0]
    {
        const float* ep = out + (size_t)(bbase + 4 * g) * NH + h;
        e0 = ep[0 * NH]; e1 = ep[1 * NH]; e2 = ep[2 * NH]; e3 = ep[3 * NH];
    }
    __syncthreads();   // Wf ready

    for (int t = 0; t < T_STEPS; ++t) {
        // ---- A-frags: y(t) row c, 16 B per kb, as 2 relaxed agent b64 loads
        // (bypass L1/L2 -> cannot observe stale double-buffer contents) ----
        const unsigned long long* __restrict__ ysrc = (const unsigned long long*)
            (ybuf + (size_t)(t & 1) * NB * NH + (size_t)(bbase + c) * NH + 8 * g);
        // 32 loads issued up front; compiler pipelines them.
#define LDA(KB) \
        const unsigned long long a##KB##_0 = __hip_atomic_load(ysrc + KB * 8 + 0, __ATOMIC_RELAXED, __HIP_MEMORY_SCOPE_AGENT); \
        const unsigned long long a##KB##_1 = __hip_atomic_load(ysrc + KB * 8 + 1, __ATOMIC_RELAXED, __HIP_MEMORY_SCOPE_AGENT);
        LDA(0)  LDA(1)  LDA(2)  LDA(3)  LDA(4)  LDA(5)  LDA(6)  LDA(7)
        LDA(8)  LDA(9)  LDA(10) LDA(11) LDA(12) LDA(13) LDA(14) LDA(15)
#undef LDA

        f32x4 ac0 = {0.f, 0.f, 0.f, 0.f};
        f32x4 ac1 = ac0, ac2 = ac0, ac3 = ac0;
#define MF(KB, AC)                                                           \
        {                                                                    \
            u64x2 p; p.x = a##KB##_0; p.y = a##KB##_1;                       \
            const short8 af = __builtin_bit_cast(short8, p);                 \
            AC = __builtin_amdgcn_mfma_f32_16x16x32_bf16(                    \
                af, Wf[wave][KB][lane], AC, 0, 0, 0);                        \
        }
        MF(0, ac0)  MF(1, ac1)  MF(2, ac2)  MF(3, ac3)
        MF(4, ac0)  MF(5, ac1)  MF(6, ac2)  MF(7, ac3)
        MF(8, ac0)  MF(9, ac1)  MF(10, ac2) MF(11, ac3)
        MF(12, ac0) MF(13, ac1) MF(14, ac2) MF(15, ac3)
#undef MF
        const f32x4 recv = (ac0 + ac1) + (ac2 + ac3);

        // ---- elementwise update (reference order), f32 state in-lane ----
        // C/D layout: col = lane&15 = h, row = (lane>>4)*4 + reg = batch.
#define UPD(R, XR, YR, ER)                                                   \
        {                                                                    \
            const float rec = recv[R] + bhh_r;                               \
            const float inp = ER + gain * (rec + v_r * XR);                  \
            const float yt  = YR + hdt * (al_r * tanh_fast(inp)              \
                                          - om2_r * XR - g2_r * YR);         \
            XR = XR + hdt * yt;                                              \
            YR = yt;                                                         \
        }
        UPD(0, x0, y0, e0) UPD(1, x1, y1, e1) UPD(2, x2, y2, e2) UPD(3, x3, y3, e3)
#undef UPD

        const size_t obase = ((size_t)t * NB + bbase + 4 * g) * NH + h;

        if (t == T_STEPS - 1) {
            out[obase + 0 * NH] = x0; out[obase + 1 * NH] = x1;
            out[obase + 2 * NH] = x2; out[obase + 3 * NH] = x3;
            break;
        }

        // ---- y(t+1) bf16, relaxed agent (write-through to coherence pt) ----
        {
            unsigned short* ydst = ybuf + (size_t)((t + 1) & 1) * NB * NH
                                        + (size_t)(bbase + 4 * g) * NH + h;
            __hip_atomic_store(ydst + 0 * NH, f32_to_bf16(y0),
                               __ATOMIC_RELAXED, __HIP_MEMORY_SCOPE_AGENT);
            __hip_atomic_store(ydst + 1 * NH, f32_to_bf16(y1),
                               __ATOMIC_RELAXED, __HIP_MEMORY_SCOPE_AGENT);
            __hip_atomic_store(ydst + 2 * NH, f32_to_bf16(y2),
                               __ATOMIC_RELAXED, __HIP_MEMORY_SCOPE_AGENT);
            __hip_atomic_store(ydst + 3 * NH, f32_to_bf16(y3),
                               __ATOMIC_RELAXED, __HIP_MEMORY_SCOPE_AGENT);
        }

        // ---- group barrier: relaxed flag store, no fences ----
        asm volatile("s_waitcnt vmcnt(0)" ::: "memory");  // y at coherence pt
        __syncthreads();                                  // whole WG drained
        const unsigned tgt = (unsigned)(t + 1);
        if (tid == 0)
            __hip_atomic_store(flags + grp * 64 + wgi, tgt,
                               __ATOMIC_RELAXED, __HIP_MEMORY_SCOPE_AGENT);

        // overlap with poll window: x output + e[t+1] prefetch (cached path,
        // cells private to this WG)
        out[obase + 0 * NH] = x0; out[obase + 1 * NH] = x1;
        out[obase + 2 * NH] = x2; out[obase + 3 * NH] = x3;
        e0 = out[obase + (size_t)NB * NH + 0 * NH];
        e1 = out[obase + (size_t)NB * NH + 1 * NH];
        e2 = out[obase + (size_t)NB * NH + 2 * NH];
        e3 = out[obase + (size_t)NB * NH + 3 * NH];

        if (tid == 0) {
            const unsigned long long* fl =
                (const unsigned long long*)(flags + grp * 64);
            for (;;) {
                const unsigned long long f01 =
                    __hip_atomic_load(fl + 0, __ATOMIC_RELAXED, __HIP_MEMORY_SCOPE_AGENT);
                const unsigned long long f23 =
                    __hip_atomic_load(fl + 1, __ATOMIC_RELAXED, __HIP_MEMORY_SCOPE_AGENT);
                if ((unsigned)f01 >= tgt && (unsigned)(f01 >> 32) >= tgt &&
                    (unsigned)f23 >= tgt && (unsigned)(f23 >> 32) >= tgt) break;
                __builtin_amdgcn_s_sleep(1);
            }
        }
        __syncthreads();   // releases WG; y loads (atomic) issue after this
    }
}

// ---------------------------------------------------------------------------
extern "C" void kernel_launch(void* const* d_in, const int* in_sizes, int n_in,
                              void* d_out, int out_size, void* d_ws, size_t ws_size,
                              hipStream_t stream) {
    const float* inputs = (const float*)d_in[0];
    const float* W_ih   = (const float*)d_in[1];
    const float* b_ih   = (const float*)d_in[2];
    const float* W_hh   = (const float*)d_in[3];
    const float* b_hh   = (const float*)d_in[4];
    const float* alpha  = (const float*)d_in[5];
    const float* omega  = (const float*)d_in[6];
    const float* gamma  = (const float*)d_in[7];
    const float* v      = (const float*)d_in[8];
    float* out = (float*)d_out;

    unsigned* flags      = (unsigned*)d_ws;
    unsigned short* ybuf = (unsigned short*)((char*)d_ws + WS_YBUF_OFF);

    // zero flags + bf16 y slot 0 (d_ws re-poisoned every launch)
    hipMemsetAsync(d_ws, 0, WS_INIT_BYTES, stream);

    // ext = inputs @ W_ih + b_ih, written into d_out (overwritten step-by-step)
    ext_gemm_kernel<<<dim3(1024), dim3(256), 0, stream>>>(inputs, W_ih, b_ih, out);

    // sequential scan: 16 WGs (4 groups x 4 h-slices) x 512 threads
    horn_recurrent_kernel<<<dim3(NGRP * WGS_PER_GRP), dim3(512), 0, stream>>>(
        W_hh, b_hh, alpha, omega, gamma, v, out, ybuf, flags);
}